// Round 2
// baseline (2314.926 us; speedup 1.0000x reference)
//
#include <hip/hip_runtime.h>

// Problem constants
#define M_ROWS 16384   // 32*512 z vectors
#define N_CB   8192    // codebook entries
#define KDIM   256     // code dim

// GEMM tiling
#define BM 64
#define BN 128
#define BK 16
#define TM 4
#define TN 8
#define NSPLIT 8
#define CODES_PER_SPLIT (N_CB / NSPLIT)      // 1024
#define CT_PER_SPLIT (CODES_PER_SPLIT / BN)  // 8
#define KC_COUNT (KDIM / BK)                 // 16

#define FLTMAX 3.402823466e+38f

// ---------------- zero counts ----------------
__global__ __launch_bounds__(256) void zero_counts_kernel(int* counts) {
  int g = blockIdx.x * 256 + threadIdx.x;
  if (g < N_CB) counts[g] = 0;
}

// ---------------- row squared norms (one wave per row) ----------------
__global__ __launch_bounds__(256) void rowsq_kernel(const float4* __restrict__ ze4,
                                                    const float4* __restrict__ cb4,
                                                    float* __restrict__ z2,
                                                    float* __restrict__ e2) {
  int wave = blockIdx.x * 4 + (threadIdx.x >> 6);
  int lane = threadIdx.x & 63;
  float4 v;
  if (wave < M_ROWS) v = ze4[(size_t)wave * 64 + lane];
  else               v = cb4[(size_t)(wave - M_ROWS) * 64 + lane];
  float s = v.x * v.x + v.y * v.y + v.z * v.z + v.w * v.w;
  #pragma unroll
  for (int off = 32; off > 0; off >>= 1) s += __shfl_down(s, off, 64);
  if (lane == 0) {
    if (wave < M_ROWS) z2[wave] = s;
    else               e2[wave - M_ROWS] = s;
  }
}

// ---------------- fused distance GEMM + argmin ----------------
// dist = fl(fl(z2 + e2) - fl(2*dot)) to replicate reference fp32 rounding;
// argmin tie rule: smallest value, then smallest code index.
// Per-thread code ownership: codes {tx*4..tx*4+3} and {64+tx*4..64+tx*4+3}
// within each BN tile, so each B ds_read_b128 spans only 64 dwords
// (2-way bank aliasing = free) instead of 128 (4-way conflict).
__global__ __launch_bounds__(256, 8) void dist_argmin_kernel(
    const float* __restrict__ A,   // z_e  (M_ROWS x KDIM)
    const float* __restrict__ B,   // codebook (N_CB x KDIM)
    const float* __restrict__ z2,
    const float* __restrict__ e2,
    float* __restrict__ pval,      // NSPLIT x M_ROWS partial min values
    int* __restrict__ pidx) {      // NSPLIT x M_ROWS partial argmin
  // 12800 B shared, reused for the final reduction (8704 B needed there)
  __shared__ char smem[(BK * (BM + 4) + BK * (BN + 4)) * 4];
  float (*As)[BM + 4] = reinterpret_cast<float (*)[BM + 4]>(smem);
  float (*Bs)[BN + 4] = reinterpret_cast<float (*)[BN + 4]>(smem + BK * (BM + 4) * 4);

  const int tid = threadIdx.x;
  const int tx = tid & 15;        // code dim, 8 codes each
  const int ty = tid >> 4;        // row dim, 4 rows each
  const int mb = blockIdx.x * BM;
  const int nb0 = blockIdx.y * CODES_PER_SPLIT;

  // global->LDS load mapping
  const int arow = tid >> 2, akq = tid & 3;                 // A: 1 float4 / thread
  const int brow0 = tid >> 1, bkq0 = (tid * 2) & 3;          // B: 2 float4 / thread
  const int brow1 = (tid * 2 + 1) >> 2, bkq1 = (tid * 2 + 1) & 3;

  const float* Abase = A + (size_t)(mb + arow) * KDIM + akq * 4;

  float z2r[TM];
  #pragma unroll
  for (int i = 0; i < TM; i++) z2r[i] = z2[mb + ty * TM + i];

  float bestv[TM]; int besti[TM];
  #pragma unroll
  for (int i = 0; i < TM; i++) { bestv[i] = FLTMAX; besti[i] = 0; }

  for (int ct = 0; ct < CT_PER_SPLIT; ct++) {
    const int nb = nb0 + ct * BN;
    const float* Bbase = B + (size_t)nb * KDIM;

    float acc[TM][TN];
    #pragma unroll
    for (int i = 0; i < TM; i++)
      #pragma unroll
      for (int j = 0; j < TN; j++) acc[i][j] = 0.0f;

    // prefetch first k-chunk into registers
    float4 pa  = *(const float4*)(Abase);
    float4 pb0 = *(const float4*)(Bbase + (size_t)brow0 * KDIM + bkq0 * 4);
    float4 pb1 = *(const float4*)(Bbase + (size_t)brow1 * KDIM + bkq1 * 4);

    for (int kc = 0; kc < KC_COUNT; kc++) {
      __syncthreads();   // previous compute done; LDS free to overwrite
      As[akq * 4 + 0][arow] = pa.x;
      As[akq * 4 + 1][arow] = pa.y;
      As[akq * 4 + 2][arow] = pa.z;
      As[akq * 4 + 3][arow] = pa.w;
      Bs[bkq0 * 4 + 0][brow0] = pb0.x;
      Bs[bkq0 * 4 + 1][brow0] = pb0.y;
      Bs[bkq0 * 4 + 2][brow0] = pb0.z;
      Bs[bkq0 * 4 + 3][brow0] = pb0.w;
      Bs[bkq1 * 4 + 0][brow1] = pb1.x;
      Bs[bkq1 * 4 + 1][brow1] = pb1.y;
      Bs[bkq1 * 4 + 2][brow1] = pb1.z;
      Bs[bkq1 * 4 + 3][brow1] = pb1.w;
      __syncthreads();
      if (kc + 1 < KC_COUNT) {   // prefetch next chunk, overlaps compute
        pa  = *(const float4*)(Abase + (kc + 1) * BK);
        pb0 = *(const float4*)(Bbase + (size_t)brow0 * KDIM + (kc + 1) * BK + bkq0 * 4);
        pb1 = *(const float4*)(Bbase + (size_t)brow1 * KDIM + (kc + 1) * BK + bkq1 * 4);
      }
      #pragma unroll
      for (int k = 0; k < BK; k++) {
        float4 a4  = *(const float4*)&As[k][ty * TM];
        float4 b4a = *(const float4*)&Bs[k][tx * 4];        // codes tx*4..+3
        float4 b4b = *(const float4*)&Bs[k][64 + tx * 4];   // codes 64+tx*4..+3
        float af[TM] = {a4.x, a4.y, a4.z, a4.w};
        float bf[TN] = {b4a.x, b4a.y, b4a.z, b4a.w, b4b.x, b4b.y, b4b.z, b4b.w};
        #pragma unroll
        for (int i = 0; i < TM; i++)
          #pragma unroll
          for (int j = 0; j < TN; j++)
            acc[i][j] = fmaf(af[i], bf[j], acc[i][j]);
      }
    }

    // epilogue: distances + running argmin.
    // j=0..3 -> code nb+tx*4+j ; j=4..7 -> code nb+64+tx*4+(j-4)
    // Both ascending in j, and all of this ct-tile's codes < next ct's codes,
    // so "first strict <" keeps the lowest index on exact ties.
    float e2v[TN];
    #pragma unroll
    for (int j = 0; j < TN; j++) {
      int code = nb + ((j < 4) ? (tx * 4 + j) : (64 + tx * 4 + (j - 4)));
      e2v[j] = e2[code];
    }
    #pragma unroll
    for (int i = 0; i < TM; i++) {
      #pragma unroll
      for (int j = 0; j < TN; j++) {
        int code = nb + ((j < 4) ? (tx * 4 + j) : (64 + tx * 4 + (j - 4)));
        float s = z2r[i] + e2v[j];           // fp32 round, as reference
        float dist = s - 2.0f * acc[i][j];   // 2*acc exact; single subtract round
        if (dist < bestv[i]) { bestv[i] = dist; besti[i] = code; }
      }
    }
  }

  // cross-tx reduction per row (lexicographic: value, then code index).
  // Reuse the GEMM LDS (guarded by barriers).
  __syncthreads();
  float (*redv)[17] = reinterpret_cast<float (*)[17]>(smem);
  int   (*redi)[17] = reinterpret_cast<int (*)[17]>(smem + BM * 17 * 4);
  #pragma unroll
  for (int i = 0; i < TM; i++) {
    redv[ty * TM + i][tx] = bestv[i];
    redi[ty * TM + i][tx] = besti[i];
  }
  __syncthreads();
  if (tid < BM) {
    float bv = redv[tid][0]; int bi = redi[tid][0];
    #pragma unroll
    for (int t = 1; t < 16; t++) {
      float v = redv[tid][t]; int i2 = redi[tid][t];
      if (v < bv || (v == bv && i2 < bi)) { bv = v; bi = i2; }
    }
    pval[(size_t)blockIdx.y * M_ROWS + mb + tid] = bv;
    pidx[(size_t)blockIdx.y * M_ROWS + mb + tid] = bi;
  }
}

// ---------------- merge split partials ----------------
__global__ __launch_bounds__(256) void merge_kernel(const float* __restrict__ pval,
                                                    const int* __restrict__ pidx,
                                                    int* __restrict__ idx_out,
                                                    float* __restrict__ codes_out) {
  int r = blockIdx.x * 256 + threadIdx.x;
  float bv = pval[r]; int bi = pidx[r];
  #pragma unroll
  for (int s = 1; s < NSPLIT; s++) {
    float v = pval[(size_t)s * M_ROWS + r];
    int i2  = pidx[(size_t)s * M_ROWS + r];
    if (v < bv || (v == bv && i2 < bi)) { bv = v; bi = i2; }
  }
  idx_out[r] = bi;
  codes_out[r] = (float)bi;
}

// ---------------- gather z_q, write z_q_st, loss partials, histogram ----------------
// One wave handles exactly one row (64 float4 per row).
__global__ __launch_bounds__(256) void gather_kernel(const float4* __restrict__ ze4,
                                                     const float4* __restrict__ cb4,
                                                     const int* __restrict__ idx,
                                                     float4* __restrict__ out4,
                                                     float* __restrict__ lpart,
                                                     int* __restrict__ counts) {
  int g = blockIdx.x * 256 + threadIdx.x;   // 0 .. 1048575
  int row = g >> 6;
  int c4 = g & 63;
  int lane = threadIdx.x & 63;
  int code = idx[row];
  float4 z = ze4[(size_t)row * 64 + c4];
  float4 e = cb4[(size_t)code * 64 + c4];
  float dx = e.x - z.x, dy = e.y - z.y, dz = e.z - z.z, dw = e.w - z.w;
  float4 o;
  o.x = z.x + dx; o.y = z.y + dy; o.z = z.z + dz; o.w = z.w + dw;  // z_e + (z_q - z_e)
  out4[(size_t)row * 64 + c4] = o;
  float ls = dx * dx + dy * dy + dz * dz + dw * dw;
  #pragma unroll
  for (int off = 32; off > 0; off >>= 1) ls += __shfl_down(ls, off, 64);
  __shared__ float sred[4];
  if (lane == 0) {
    sred[threadIdx.x >> 6] = ls;
    atomicAdd(&counts[code], 1);   // exactly one wave per row
  }
  __syncthreads();
  if (threadIdx.x == 0) lpart[blockIdx.x] = sred[0] + sred[1] + sred[2] + sred[3];
}

// ---------------- finalize scalars ----------------
__global__ __launch_bounds__(256) void finalize_kernel(const float* __restrict__ lpart,
                                                       const int* __restrict__ counts,
                                                       float* __restrict__ out_scalars) {
  __shared__ double sd[256];
  double s = 0.0;
  for (int i = threadIdx.x; i < 4096; i += 256) s += (double)lpart[i];
  sd[threadIdx.x] = s;
  __syncthreads();
  for (int st = 128; st > 0; st >>= 1) {
    if (threadIdx.x < st) sd[threadIdx.x] += sd[threadIdx.x + st];
    __syncthreads();
  }
  double totalLoss = sd[0];
  __syncthreads();
  double ps = 0.0;
  for (int c = threadIdx.x; c < N_CB; c += 256) {
    float avg = (float)counts[c] * (1.0f / 16384.0f);   // exact (div by 2^14)
    ps += (double)(avg * logf(avg + 1e-10f));
  }
  sd[threadIdx.x] = ps;
  __syncthreads();
  for (int st = 128; st > 0; st >>= 1) {
    if (threadIdx.x < st) sd[threadIdx.x] += sd[threadIdx.x + st];
    __syncthreads();
  }
  if (threadIdx.x == 0) {
    float mean = (float)(totalLoss / 4194304.0);  // mean over 16384*256 elements
    float lv = mean + 0.25f * mean;               // loss_cb + BETA*loss_commit (equal values)
    out_scalars[0] = lv;
    out_scalars[1] = expf(-(float)sd[0]);
  }
}

extern "C" void kernel_launch(void* const* d_in, const int* in_sizes, int n_in,
                              void* d_out, int out_size, void* d_ws, size_t ws_size,
                              hipStream_t stream) {
  const float* z_e = (const float*)d_in[0];   // 32*512*256
  const float* cb  = (const float*)d_in[1];   // 8192*256
  float* out = (float*)d_out;
  // out layout: [0,4194304) z_q_st | [4194304,4210688) codes(float) | loss | perplexity

  char* ws = (char*)d_ws;
  float* z2     = (float*)(ws + 0);           // 16384 f32 (64 KB)
  float* e2     = (float*)(ws + 65536);       // 8192 f32 (32 KB)
  float* pval   = (float*)(ws + 98304);       // NSPLIT*16384 f32 (512 KB)
  int*   pidx   = (int*)  (ws + 622592);      // NSPLIT*16384 i32 (512 KB)
  int*   idxf   = (int*)  (ws + 1146880);     // 16384 i32 (64 KB)
  int*   counts = (int*)  (ws + 1212416);     // 8192 i32 (32 KB)
  float* lpart  = (float*)(ws + 1245184);     // 4096 f32 (16 KB)
  // total ws use: ~1.21 MB

  zero_counts_kernel<<<32, 256, 0, stream>>>(counts);
  rowsq_kernel<<<(M_ROWS + N_CB) / 4, 256, 0, stream>>>(
      (const float4*)z_e, (const float4*)cb, z2, e2);
  dim3 grid(M_ROWS / BM, NSPLIT);
  dist_argmin_kernel<<<grid, 256, 0, stream>>>(z_e, cb, z2, e2, pval, pidx);
  merge_kernel<<<M_ROWS / 256, 256, 0, stream>>>(pval, pidx, idxf, out + 4194304);
  gather_kernel<<<4096, 256, 0, stream>>>((const float4*)z_e, (const float4*)cb, idxf,
                                          (float4*)out, lpart, counts);
  finalize_kernel<<<1, 256, 0, stream>>>(lpart, counts, out + 4210688);
}

// Round 5
// 1560.500 us; speedup vs baseline: 1.4835x; 1.4835x over previous
//
#include <hip/hip_runtime.h>

// Problem constants
#define M_ROWS 16384   // 32*512 z vectors
#define N_CB   8192    // codebook entries
#define KDIM   256     // code dim

// GEMM tiling
#define BM 64
#define BN 128
#define BK 16
#define TM 4
#define TN 8
#define NSPLIT 8
#define CODES_PER_SPLIT (N_CB / NSPLIT)      // 1024
#define CT_PER_SPLIT (CODES_PER_SPLIT / BN)  // 8
#define KC_COUNT (KDIM / BK)                 // 16

#define FLTMAX 3.402823466e+38f

// ---------------- zero counts ----------------
__global__ __launch_bounds__(256) void zero_counts_kernel(int* counts) {
  int g = blockIdx.x * 256 + threadIdx.x;
  if (g < N_CB) counts[g] = 0;
}

// ---------------- row squared norms (one wave per row) ----------------
__global__ __launch_bounds__(256) void rowsq_kernel(const float4* __restrict__ ze4,
                                                    const float4* __restrict__ cb4,
                                                    float* __restrict__ z2,
                                                    float* __restrict__ e2) {
  int wave = blockIdx.x * 4 + (threadIdx.x >> 6);
  int lane = threadIdx.x & 63;
  float4 v;
  if (wave < M_ROWS) v = ze4[(size_t)wave * 64 + lane];
  else               v = cb4[(size_t)(wave - M_ROWS) * 64 + lane];
  float s = v.x * v.x + v.y * v.y + v.z * v.z + v.w * v.w;
  #pragma unroll
  for (int off = 32; off > 0; off >>= 1) s += __shfl_down(s, off, 64);
  if (lane == 0) {
    if (wave < M_ROWS) z2[wave] = s;
    else               e2[wave - M_ROWS] = s;
  }
}

// ---------------- fused distance GEMM + argmin ----------------
// dist = fl(fl(z2 + e2) - fl(2*dot)) to replicate reference fp32 rounding;
// argmin tie rule: smallest value, then smallest code index.
// Per-thread code ownership: codes {tx*4..tx*4+3} and {64+tx*4..64+tx*4+3}
// within each BN tile, so each B ds_read_b128 spans only 64 dwords
// (2-way bank aliasing = free) instead of 128 (4-way conflict).
// __launch_bounds__(256, 4): 128-VGPR cap -> compiles to 64 VGPR, no spill.
// Round 2 lesson: (256,8) capped alloc at 32 VGPR and spilled acc[] to
// scratch: 9 GB HBM traffic, 1.6x regression. Do not cap below 128.
__global__ __launch_bounds__(256, 4) void dist_argmin_kernel(
    const float* __restrict__ A,   // z_e  (M_ROWS x KDIM)
    const float* __restrict__ B,   // codebook (N_CB x KDIM)
    const float* __restrict__ z2,
    const float* __restrict__ e2,
    float* __restrict__ pval,      // NSPLIT x M_ROWS partial min values
    int* __restrict__ pidx) {      // NSPLIT x M_ROWS partial argmin
  // 12800 B shared, reused for the final reduction (8704 B needed there)
  __shared__ char smem[(BK * (BM + 4) + BK * (BN + 4)) * 4];
  float (*As)[BM + 4] = reinterpret_cast<float (*)[BM + 4]>(smem);
  float (*Bs)[BN + 4] = reinterpret_cast<float (*)[BN + 4]>(smem + BK * (BM + 4) * 4);

  const int tid = threadIdx.x;
  const int tx = tid & 15;        // code dim, 8 codes each
  const int ty = tid >> 4;        // row dim, 4 rows each
  const int mb = blockIdx.x * BM;
  const int nb0 = blockIdx.y * CODES_PER_SPLIT;

  // global->LDS load mapping
  const int arow = tid >> 2, akq = tid & 3;                 // A: 1 float4 / thread
  const int brow0 = tid >> 1, bkq0 = (tid * 2) & 3;          // B: 2 float4 / thread
  const int brow1 = (tid * 2 + 1) >> 2, bkq1 = (tid * 2 + 1) & 3;

  const float* Abase = A + (size_t)(mb + arow) * KDIM + akq * 4;

  float z2r[TM];
  #pragma unroll
  for (int i = 0; i < TM; i++) z2r[i] = z2[mb + ty * TM + i];

  float bestv[TM]; int besti[TM];
  #pragma unroll
  for (int i = 0; i < TM; i++) { bestv[i] = FLTMAX; besti[i] = 0; }

  for (int ct = 0; ct < CT_PER_SPLIT; ct++) {
    const int nb = nb0 + ct * BN;
    const float* Bbase = B + (size_t)nb * KDIM;

    float acc[TM][TN];
    #pragma unroll
    for (int i = 0; i < TM; i++)
      #pragma unroll
      for (int j = 0; j < TN; j++) acc[i][j] = 0.0f;

    // prefetch first k-chunk into registers
    float4 pa  = *(const float4*)(Abase);
    float4 pb0 = *(const float4*)(Bbase + (size_t)brow0 * KDIM + bkq0 * 4);
    float4 pb1 = *(const float4*)(Bbase + (size_t)brow1 * KDIM + bkq1 * 4);

    for (int kc = 0; kc < KC_COUNT; kc++) {
      __syncthreads();   // previous compute done; LDS free to overwrite
      As[akq * 4 + 0][arow] = pa.x;
      As[akq * 4 + 1][arow] = pa.y;
      As[akq * 4 + 2][arow] = pa.z;
      As[akq * 4 + 3][arow] = pa.w;
      Bs[bkq0 * 4 + 0][brow0] = pb0.x;
      Bs[bkq0 * 4 + 1][brow0] = pb0.y;
      Bs[bkq0 * 4 + 2][brow0] = pb0.z;
      Bs[bkq0 * 4 + 3][brow0] = pb0.w;
      Bs[bkq1 * 4 + 0][brow1] = pb1.x;
      Bs[bkq1 * 4 + 1][brow1] = pb1.y;
      Bs[bkq1 * 4 + 2][brow1] = pb1.z;
      Bs[bkq1 * 4 + 3][brow1] = pb1.w;
      __syncthreads();
      if (kc + 1 < KC_COUNT) {   // prefetch next chunk, overlaps compute
        pa  = *(const float4*)(Abase + (kc + 1) * BK);
        pb0 = *(const float4*)(Bbase + (size_t)brow0 * KDIM + (kc + 1) * BK + bkq0 * 4);
        pb1 = *(const float4*)(Bbase + (size_t)brow1 * KDIM + (kc + 1) * BK + bkq1 * 4);
      }
      #pragma unroll
      for (int k = 0; k < BK; k++) {
        float4 a4  = *(const float4*)&As[k][ty * TM];
        float4 b4a = *(const float4*)&Bs[k][tx * 4];        // codes tx*4..+3
        float4 b4b = *(const float4*)&Bs[k][64 + tx * 4];   // codes 64+tx*4..+3
        float af[TM] = {a4.x, a4.y, a4.z, a4.w};
        float bf[TN] = {b4a.x, b4a.y, b4a.z, b4a.w, b4b.x, b4b.y, b4b.z, b4b.w};
        #pragma unroll
        for (int i = 0; i < TM; i++)
          #pragma unroll
          for (int j = 0; j < TN; j++)
            acc[i][j] = fmaf(af[i], bf[j], acc[i][j]);
      }
    }

    // epilogue: distances + running argmin.
    // j=0..3 -> code nb+tx*4+j ; j=4..7 -> code nb+64+tx*4+(j-4)
    // Both ascending in j, and all of this ct-tile's codes < next ct's codes,
    // so "first strict <" keeps the lowest index on exact ties.
    float e2v[TN];
    #pragma unroll
    for (int j = 0; j < TN; j++) {
      int code = nb + ((j < 4) ? (tx * 4 + j) : (64 + tx * 4 + (j - 4)));
      e2v[j] = e2[code];
    }
    #pragma unroll
    for (int i = 0; i < TM; i++) {
      #pragma unroll
      for (int j = 0; j < TN; j++) {
        int code = nb + ((j < 4) ? (tx * 4 + j) : (64 + tx * 4 + (j - 4)));
        float s = z2r[i] + e2v[j];           // fp32 round, as reference
        float dist = s - 2.0f * acc[i][j];   // 2*acc exact; single subtract round
        if (dist < bestv[i]) { bestv[i] = dist; besti[i] = code; }
      }
    }
  }

  // cross-tx reduction per row (lexicographic: value, then code index).
  // Reuse the GEMM LDS (guarded by barriers).
  __syncthreads();
  float (*redv)[17] = reinterpret_cast<float (*)[17]>(smem);
  int   (*redi)[17] = reinterpret_cast<int (*)[17]>(smem + BM * 17 * 4);
  #pragma unroll
  for (int i = 0; i < TM; i++) {
    redv[ty * TM + i][tx] = bestv[i];
    redi[ty * TM + i][tx] = besti[i];
  }
  __syncthreads();
  if (tid < BM) {
    float bv = redv[tid][0]; int bi = redi[tid][0];
    #pragma unroll
    for (int t = 1; t < 16; t++) {
      float v = redv[tid][t]; int i2 = redi[tid][t];
      if (v < bv || (v == bv && i2 < bi)) { bv = v; bi = i2; }
    }
    pval[(size_t)blockIdx.y * M_ROWS + mb + tid] = bv;
    pidx[(size_t)blockIdx.y * M_ROWS + mb + tid] = bi;
  }
}

// ---------------- merge split partials ----------------
__global__ __launch_bounds__(256) void merge_kernel(const float* __restrict__ pval,
                                                    const int* __restrict__ pidx,
                                                    int* __restrict__ idx_out,
                                                    float* __restrict__ codes_out) {
  int r = blockIdx.x * 256 + threadIdx.x;
  float bv = pval[r]; int bi = pidx[r];
  #pragma unroll
  for (int s = 1; s < NSPLIT; s++) {
    float v = pval[(size_t)s * M_ROWS + r];
    int i2  = pidx[(size_t)s * M_ROWS + r];
    if (v < bv || (v == bv && i2 < bi)) { bv = v; bi = i2; }
  }
  idx_out[r] = bi;
  codes_out[r] = (float)bi;
}

// ---------------- gather z_q, write z_q_st, loss partials, histogram ----------------
// One wave handles exactly one row (64 float4 per row).
__global__ __launch_bounds__(256) void gather_kernel(const float4* __restrict__ ze4,
                                                     const float4* __restrict__ cb4,
                                                     const int* __restrict__ idx,
                                                     float4* __restrict__ out4,
                                                     float* __restrict__ lpart,
                                                     int* __restrict__ counts) {
  int g = blockIdx.x * 256 + threadIdx.x;   // 0 .. 1048575
  int row = g >> 6;
  int c4 = g & 63;
  int lane = threadIdx.x & 63;
  int code = idx[row];
  float4 z = ze4[(size_t)row * 64 + c4];
  float4 e = cb4[(size_t)code * 64 + c4];
  float dx = e.x - z.x, dy = e.y - z.y, dz = e.z - z.z, dw = e.w - z.w;
  float4 o;
  o.x = z.x + dx; o.y = z.y + dy; o.z = z.z + dz; o.w = z.w + dw;  // z_e + (z_q - z_e)
  out4[(size_t)row * 64 + c4] = o;
  float ls = dx * dx + dy * dy + dz * dz + dw * dw;
  #pragma unroll
  for (int off = 32; off > 0; off >>= 1) ls += __shfl_down(ls, off, 64);
  __shared__ float sred[4];
  if (lane == 0) {
    sred[threadIdx.x >> 6] = ls;
    atomicAdd(&counts[code], 1);   // exactly one wave per row
  }
  __syncthreads();
  if (threadIdx.x == 0) lpart[blockIdx.x] = sred[0] + sred[1] + sred[2] + sred[3];
}

// ---------------- finalize scalars ----------------
__global__ __launch_bounds__(256) void finalize_kernel(const float* __restrict__ lpart,
                                                       const int* __restrict__ counts,
                                                       float* __restrict__ out_scalars) {
  __shared__ double sd[256];
  double s = 0.0;
  for (int i = threadIdx.x; i < 4096; i += 256) s += (double)lpart[i];
  sd[threadIdx.x] = s;
  __syncthreads();
  for (int st = 128; st > 0; st >>= 1) {
    if (threadIdx.x < st) sd[threadIdx.x] += sd[threadIdx.x + st];
    __syncthreads();
  }
  double totalLoss = sd[0];
  __syncthreads();
  double ps = 0.0;
  for (int c = threadIdx.x; c < N_CB; c += 256) {
    float avg = (float)counts[c] * (1.0f / 16384.0f);   // exact (div by 2^14)
    ps += (double)(avg * logf(avg + 1e-10f));
  }
  sd[threadIdx.x] = ps;
  __syncthreads();
  for (int st = 128; st > 0; st >>= 1) {
    if (threadIdx.x < st) sd[threadIdx.x] += sd[threadIdx.x + st];
    __syncthreads();
  }
  if (threadIdx.x == 0) {
    float mean = (float)(totalLoss / 4194304.0);  // mean over 16384*256 elements
    float lv = mean + 0.25f * mean;               // loss_cb + BETA*loss_commit (equal values)
    out_scalars[0] = lv;
    out_scalars[1] = expf(-(float)sd[0]);
  }
}

extern "C" void kernel_launch(void* const* d_in, const int* in_sizes, int n_in,
                              void* d_out, int out_size, void* d_ws, size_t ws_size,
                              hipStream_t stream) {
  const float* z_e = (const float*)d_in[0];   // 32*512*256
  const float* cb  = (const float*)d_in[1];   // 8192*256
  float* out = (float*)d_out;
  // out layout: [0,4194304) z_q_st | [4194304,4210688) codes(float) | loss | perplexity

  char* ws = (char*)d_ws;
  float* z2     = (float*)(ws + 0);           // 16384 f32 (64 KB)
  float* e2     = (float*)(ws + 65536);       // 8192 f32 (32 KB)
  float* pval   = (float*)(ws + 98304);       // NSPLIT*16384 f32 (512 KB)
  int*   pidx   = (int*)  (ws + 622592);      // NSPLIT*16384 i32 (512 KB)
  int*   idxf   = (int*)  (ws + 1146880);     // 16384 i32 (64 KB)
  int*   counts = (int*)  (ws + 1212416);     // 8192 i32 (32 KB)
  float* lpart  = (float*)(ws + 1245184);     // 4096 f32 (16 KB)
  // total ws use: ~1.21 MB

  zero_counts_kernel<<<32, 256, 0, stream>>>(counts);
  rowsq_kernel<<<(M_ROWS + N_CB) / 4, 256, 0, stream>>>(
      (const float4*)z_e, (const float4*)cb, z2, e2);
  dim3 grid(M_ROWS / BM, NSPLIT);
  dist_argmin_kernel<<<grid, 256, 0, stream>>>(z_e, cb, z2, e2, pval, pidx);
  merge_kernel<<<M_ROWS / 256, 256, 0, stream>>>(pval, pidx, idxf, out + 4194304);
  gather_kernel<<<4096, 256, 0, stream>>>((const float4*)z_e, (const float4*)cb, idxf,
                                          (float4*)out, lpart, counts);
  finalize_kernel<<<1, 256, 0, stream>>>(lpart, counts, out + 4210688);
}

// Round 6
// 809.203 us; speedup vs baseline: 2.8607x; 1.9284x over previous
//
#include <hip/hip_runtime.h>

// Problem constants
#define M_ROWS 16384   // 32*512 z vectors
#define N_CB   8192    // codebook entries
#define KDIM   256     // code dim
#define NSPLIT 8
#define SPLITC (N_CB / NSPLIT)   // 1024 codes per split
#define BM 64          // z rows per block in mfma kernel

#define FLTMAX 3.402823466e+38f

typedef __attribute__((ext_vector_type(8))) short short8v;  // 8 bf16 (4 VGPRs)
typedef __attribute__((ext_vector_type(4))) float f32x4;    // MFMA accumulator

__device__ __forceinline__ ushort bf16_rne(float x) {
  unsigned u = __float_as_uint(x);
  return (ushort)((u + 0x7FFF + ((u >> 16) & 1)) >> 16);   // RNE truncate to bf16
}

// ---------------- zero counts ----------------
__global__ __launch_bounds__(256) void zero_counts_kernel(int* counts) {
  int g = blockIdx.x * 256 + threadIdx.x;
  if (g < N_CB) counts[g] = 0;
}

// ---------------- row squared norms (one wave per row) ----------------
__global__ __launch_bounds__(256) void rowsq_kernel(const float4* __restrict__ ze4,
                                                    const float4* __restrict__ cb4,
                                                    float* __restrict__ z2,
                                                    float* __restrict__ e2) {
  int wave = blockIdx.x * 4 + (threadIdx.x >> 6);
  int lane = threadIdx.x & 63;
  float4 v;
  if (wave < M_ROWS) v = ze4[(size_t)wave * 64 + lane];
  else               v = cb4[(size_t)(wave - M_ROWS) * 64 + lane];
  float s = v.x * v.x + v.y * v.y + v.z * v.z + v.w * v.w;
  #pragma unroll
  for (int off = 32; off > 0; off >>= 1) s += __shfl_down(s, off, 64);
  if (lane == 0) {
    if (wave < M_ROWS) z2[wave] = s;
    else               e2[wave - M_ROWS] = s;
  }
}

// ---------------- codebook fp32 -> bf16 hi/lo split ----------------
__global__ __launch_bounds__(256) void cbsplit_kernel(const float4* __restrict__ cb4,
                                                      ushort4* __restrict__ ch4,
                                                      ushort4* __restrict__ cl4) {
  int g = blockIdx.x * 256 + threadIdx.x;    // 0 .. 524287 (8192*64 float4)
  float4 v = cb4[g];
  ushort h0 = bf16_rne(v.x), h1 = bf16_rne(v.y), h2 = bf16_rne(v.z), h3 = bf16_rne(v.w);
  float r0 = v.x - __uint_as_float((unsigned)h0 << 16);
  float r1 = v.y - __uint_as_float((unsigned)h1 << 16);
  float r2 = v.z - __uint_as_float((unsigned)h2 << 16);
  float r3 = v.w - __uint_as_float((unsigned)h3 << 16);
  ch4[g] = make_ushort4(h0, h1, h2, h3);
  cl4[g] = make_ushort4(bf16_rne(r0), bf16_rne(r1), bf16_rne(r2), bf16_rne(r3));
}

// ---------------- MFMA approx dist + per-(row,split) top-2 candidates ----------------
// dot(z,e) ~ zh*eh + zh*el + zl*eh (3 bf16 MFMAs into one fp32 acc), err ~1e-8.
// MFMA roles: A = codebook tile (16 codes x 32 k), B = z tile (32 k x 16 rows).
// Layouts (gfx950 16x16x32): A: lane l elem j -> A[l&15][(l>>4)*8+j];
// B: lane l elem j -> B[(l>>4)*8+j][l&15]; D: lane l reg r -> D[(l>>4)*4+r][l&15].
// So each lane owns ONE z-row column per tile -> per-lane top-2 state is small.
// z tile staged in LDS as bf16 hi/lo, XOR-swizzled 16B chunks (unpadded 512B rows
// would be a 16-way bank conflict; chunk^(row&7) balances all 32 banks).
__global__ __launch_bounds__(256) void mfma_topk_kernel(
    const float* __restrict__ A,      // z_e fp32 [16384][256]
    const ushort* __restrict__ ch,    // codebook hi bf16 bits [8192][256]
    const ushort* __restrict__ cl,    // codebook lo bf16 bits
    const float* __restrict__ z2,
    const float* __restrict__ e2,
    int* __restrict__ pc2) {          // [NSPLIT][16384][2] candidate indices
  __shared__ ushort smem[2][BM][256];   // 64 KB total (hi, lo)

  const int tid = threadIdx.x;
  const int w   = tid >> 6;        // wave 0..3
  const int l   = tid & 63;
  const int lg  = l >> 4;          // k-group / n-subgroup
  const int lr  = l & 15;          // z-row within tile / code within A tile
  const int xr  = lr & 7;
  const int mb  = blockIdx.x * BM;
  const int nb0 = blockIdx.y * SPLITC;

  // ---- stage z fp32 -> bf16 hi/lo into swizzled LDS ----
  #pragma unroll
  for (int i = 0; i < 16; i++) {
    int cidx = tid + 256 * i;            // float4 chunk id, 0..4095
    int row  = cidx >> 6;                // 64 float4 per row
    int c4   = cidx & 63;
    float4 v = *(const float4*)(A + (size_t)(mb + row) * KDIM + c4 * 4);
    ushort h0 = bf16_rne(v.x), h1 = bf16_rne(v.y), h2 = bf16_rne(v.z), h3 = bf16_rne(v.w);
    float l0 = v.x - __uint_as_float((unsigned)h0 << 16);
    float l1 = v.y - __uint_as_float((unsigned)h1 << 16);
    float l2 = v.z - __uint_as_float((unsigned)h2 << 16);
    float l3 = v.w - __uint_as_float((unsigned)h3 << 16);
    int chunk = c4 >> 1, half = c4 & 1;
    int uoff = row * 256 + (((chunk ^ (row & 7)) << 3) | (half << 2));
    *(ushort4*)((ushort*)smem[0] + uoff) = make_ushort4(h0, h1, h2, h3);
    *(ushort4*)((ushort*)smem[1] + uoff) =
        make_ushort4(bf16_rne(l0), bf16_rne(l1), bf16_rne(l2), bf16_rne(l3));
  }

  float z2v[4];
  #pragma unroll
  for (int bt = 0; bt < 4; bt++) z2v[bt] = z2[mb + bt * 16 + lr];

  float bv1[4], bv2[4]; int bi1[4], bi2[4];
  #pragma unroll
  for (int bt = 0; bt < 4; bt++) {
    bv1[bt] = FLTMAX; bv2[bt] = FLTMAX; bi1[bt] = 0x7fffffff; bi2[bt] = 0x7fffffff;
  }

  __syncthreads();

  // ---- 8 passes x 32 codes per wave (4 waves cover 1024 codes of the split) ----
  for (int p = 0; p < 8; p++) {
    const int nbase = nb0 + (p * 4 + w) * 32;   // ascending over p per lane
    const ushort* a0h = ch + (size_t)(nbase + lr) * KDIM + lg * 8;
    const ushort* a0l = cl + (size_t)(nbase + lr) * KDIM + lg * 8;
    const ushort* a1h = a0h + 16 * KDIM;
    const ushort* a1l = a0l + 16 * KDIM;

    f32x4 acc[2][4];
    #pragma unroll
    for (int nt = 0; nt < 2; nt++)
      #pragma unroll
      for (int bt = 0; bt < 4; bt++) acc[nt][bt] = f32x4{0.f, 0.f, 0.f, 0.f};

    #pragma unroll
    for (int ks = 0; ks < 8; ks++) {
      short8v ah0 = *(const short8v*)(a0h + ks * 32);
      short8v al0 = *(const short8v*)(a0l + ks * 32);
      short8v ah1 = *(const short8v*)(a1h + ks * 32);
      short8v al1 = *(const short8v*)(a1l + ks * 32);
      const int inner = ((ks * 4 + lg) ^ xr) << 3;
      #pragma unroll
      for (int bt = 0; bt < 4; bt++) {
        int uoff = (bt * 16 + lr) * 256 + inner;
        short8v bh = *(const short8v*)((const ushort*)smem[0] + uoff);
        short8v bl = *(const short8v*)((const ushort*)smem[1] + uoff);
        acc[0][bt] = __builtin_amdgcn_mfma_f32_16x16x32_bf16(ah0, bh, acc[0][bt], 0, 0, 0);
        acc[0][bt] = __builtin_amdgcn_mfma_f32_16x16x32_bf16(ah0, bl, acc[0][bt], 0, 0, 0);
        acc[0][bt] = __builtin_amdgcn_mfma_f32_16x16x32_bf16(al0, bh, acc[0][bt], 0, 0, 0);
        acc[1][bt] = __builtin_amdgcn_mfma_f32_16x16x32_bf16(ah1, bh, acc[1][bt], 0, 0, 0);
        acc[1][bt] = __builtin_amdgcn_mfma_f32_16x16x32_bf16(ah1, bl, acc[1][bt], 0, 0, 0);
        acc[1][bt] = __builtin_amdgcn_mfma_f32_16x16x32_bf16(al1, bh, acc[1][bt], 0, 0, 0);
      }
    }

    float4 e2v0 = *(const float4*)(e2 + nbase + lg * 4);
    float4 e2v1 = *(const float4*)(e2 + nbase + 16 + lg * 4);
    float e2a[2][4] = {{e2v0.x, e2v0.y, e2v0.z, e2v0.w},
                       {e2v1.x, e2v1.y, e2v1.z, e2v1.w}};
    #pragma unroll
    for (int nt = 0; nt < 2; nt++) {
      #pragma unroll
      for (int r = 0; r < 4; r++) {
        int n = nbase + nt * 16 + lg * 4 + r;   // ascending per lane -> strict < = lowest idx
        #pragma unroll
        for (int bt = 0; bt < 4; bt++) {
          float s = z2v[bt] + e2a[nt][r];
          float d = s - 2.0f * acc[nt][bt][r];
          if (d < bv1[bt]) { bv2[bt] = bv1[bt]; bi2[bt] = bi1[bt]; bv1[bt] = d; bi1[bt] = n; }
          else if (d < bv2[bt]) { bv2[bt] = d; bi2[bt] = n; }
        }
      }
    }
  }

  // ---- block-level top-2 merge per row (reuse LDS) ----
  __syncthreads();
  float* mv = (float*)&smem[0][0][0];   // [64][32]
  int*   mi = (int*)  &smem[1][0][0];   // [64][32]
  int slot = (w * 4 + lg) * 2;
  #pragma unroll
  for (int bt = 0; bt < 4; bt++) {
    int row = bt * 16 + lr;
    mv[row * 32 + slot]     = bv1[bt];  mi[row * 32 + slot]     = bi1[bt];
    mv[row * 32 + slot + 1] = bv2[bt];  mi[row * 32 + slot + 1] = bi2[bt];
  }
  __syncthreads();
  if (tid < BM) {
    float v1 = FLTMAX, v2 = FLTMAX; int i1 = 0x7fffffff, i2 = 0x7fffffff;
    for (int s = 0; s < 32; s++) {
      float v = mv[tid * 32 + s]; int ii = mi[tid * 32 + s];
      if (v < v1 || (v == v1 && ii < i1)) { v2 = v1; i2 = i1; v1 = v; i1 = ii; }
      else if (v < v2 || (v == v2 && ii < i2)) { v2 = v; i2 = ii; }
    }
    size_t gr = (size_t)blockIdx.y * M_ROWS + (mb + tid);
    pc2[gr * 2]     = i1;
    pc2[gr * 2 + 1] = i2;
  }
}

// ---------------- exact fp32 refinement over 16 candidates per row ----------------
// One wave per row, 4 lanes per candidate. dist = fl(fl(z2+e2) - fl(2*dot)),
// lexicographic (dist, idx) min -> reference-exact semantics on the candidate set.
__global__ __launch_bounds__(256) void refine_kernel(
    const float* __restrict__ z_e, const float* __restrict__ cb,
    const float* __restrict__ z2, const float* __restrict__ e2,
    const int* __restrict__ pc2,
    int* __restrict__ idxf, float* __restrict__ codes_out) {
  __shared__ float rv[4][16];
  __shared__ int   ri[4][16];
  int wv = threadIdx.x >> 6;
  int l  = threadIdx.x & 63;
  int row = blockIdx.x * 4 + wv;
  int c = l >> 2, q = l & 3;
  int split = c >> 1, ent = c & 1;
  int cand = pc2[((size_t)split * M_ROWS + row) * 2 + ent];
  const float4* zr = (const float4*)(z_e + (size_t)row * KDIM);
  const float4* cr = (const float4*)(cb + (size_t)cand * KDIM);
  float s = 0.0f;
  #pragma unroll
  for (int j = 0; j < 16; j++) {
    float4 a = zr[q + 4 * j];
    float4 b = cr[q + 4 * j];
    s = fmaf(a.x, b.x, s); s = fmaf(a.y, b.y, s);
    s = fmaf(a.z, b.z, s); s = fmaf(a.w, b.w, s);
  }
  s += __shfl_xor(s, 1);
  s += __shfl_xor(s, 2);
  if (q == 0) {
    float d = (z2[row] + e2[cand]) - 2.0f * s;
    rv[wv][c] = d; ri[wv][c] = cand;
  }
  __syncthreads();
  if (l == 0) {
    float bv = rv[wv][0]; int bi = ri[wv][0];
    for (int k = 1; k < 16; k++) {
      float v = rv[wv][k]; int ii = ri[wv][k];
      if (v < bv || (v == bv && ii < bi)) { bv = v; bi = ii; }
    }
    idxf[row] = bi;
    codes_out[row] = (float)bi;
  }
}

// ---------------- gather z_q, write z_q_st, loss partials, histogram ----------------
__global__ __launch_bounds__(256) void gather_kernel(const float4* __restrict__ ze4,
                                                     const float4* __restrict__ cb4,
                                                     const int* __restrict__ idx,
                                                     float4* __restrict__ out4,
                                                     float* __restrict__ lpart,
                                                     int* __restrict__ counts) {
  int g = blockIdx.x * 256 + threadIdx.x;
  int row = g >> 6;
  int c4 = g & 63;
  int lane = threadIdx.x & 63;
  int code = idx[row];
  float4 z = ze4[(size_t)row * 64 + c4];
  float4 e = cb4[(size_t)code * 64 + c4];
  float dx = e.x - z.x, dy = e.y - z.y, dz = e.z - z.z, dw = e.w - z.w;
  float4 o;
  o.x = z.x + dx; o.y = z.y + dy; o.z = z.z + dz; o.w = z.w + dw;
  out4[(size_t)row * 64 + c4] = o;
  float ls = dx * dx + dy * dy + dz * dz + dw * dw;
  #pragma unroll
  for (int off = 32; off > 0; off >>= 1) ls += __shfl_down(ls, off, 64);
  __shared__ float sred[4];
  if (lane == 0) {
    sred[threadIdx.x >> 6] = ls;
    atomicAdd(&counts[code], 1);
  }
  __syncthreads();
  if (threadIdx.x == 0) lpart[blockIdx.x] = sred[0] + sred[1] + sred[2] + sred[3];
}

// ---------------- finalize scalars ----------------
__global__ __launch_bounds__(256) void finalize_kernel(const float* __restrict__ lpart,
                                                       const int* __restrict__ counts,
                                                       float* __restrict__ out_scalars) {
  __shared__ double sd[256];
  double s = 0.0;
  for (int i = threadIdx.x; i < 4096; i += 256) s += (double)lpart[i];
  sd[threadIdx.x] = s;
  __syncthreads();
  for (int st = 128; st > 0; st >>= 1) {
    if (threadIdx.x < st) sd[threadIdx.x] += sd[threadIdx.x + st];
    __syncthreads();
  }
  double totalLoss = sd[0];
  __syncthreads();
  double ps = 0.0;
  for (int c = threadIdx.x; c < N_CB; c += 256) {
    float avg = (float)counts[c] * (1.0f / 16384.0f);
    ps += (double)(avg * logf(avg + 1e-10f));
  }
  sd[threadIdx.x] = ps;
  __syncthreads();
  for (int st = 128; st > 0; st >>= 1) {
    if (threadIdx.x < st) sd[threadIdx.x] += sd[threadIdx.x + st];
    __syncthreads();
  }
  if (threadIdx.x == 0) {
    float mean = (float)(totalLoss / 4194304.0);
    float lv = mean + 0.25f * mean;
    out_scalars[0] = lv;
    out_scalars[1] = expf(-(float)sd[0]);
  }
}

extern "C" void kernel_launch(void* const* d_in, const int* in_sizes, int n_in,
                              void* d_out, int out_size, void* d_ws, size_t ws_size,
                              hipStream_t stream) {
  const float* z_e = (const float*)d_in[0];   // 32*512*256
  const float* cb  = (const float*)d_in[1];   // 8192*256
  float* out = (float*)d_out;
  // out layout: [0,4194304) z_q_st | [4194304,4210688) codes(float) | loss | perplexity

  char* ws = (char*)d_ws;
  ushort* ch   = (ushort*)(ws + 0);          // 8192*256 bf16 hi (4 MB)
  ushort* cl   = (ushort*)(ws + 4194304);    // 8192*256 bf16 lo (4 MB)
  float* z2    = (float*)(ws + 8388608);     // 16384 f32 (64 KB)
  float* e2    = (float*)(ws + 8454144);     // 8192 f32 (32 KB)
  int*   pc2   = (int*)  (ws + 8486912);     // 8*16384*2 i32 (1 MB)
  int*   idxf  = (int*)  (ws + 9535488);     // 16384 i32 (64 KB)
  int*   counts= (int*)  (ws + 9601024);     // 8192 i32 (32 KB)
  float* lpart = (float*)(ws + 9633792);     // 4096 f32 (16 KB)
  // total ws use: ~9.3 MB

  zero_counts_kernel<<<32, 256, 0, stream>>>(counts);
  rowsq_kernel<<<(M_ROWS + N_CB) / 4, 256, 0, stream>>>(
      (const float4*)z_e, (const float4*)cb, z2, e2);
  cbsplit_kernel<<<2048, 256, 0, stream>>>((const float4*)cb, (ushort4*)ch, (ushort4*)cl);
  dim3 grid(M_ROWS / BM, NSPLIT);
  mfma_topk_kernel<<<grid, 256, 0, stream>>>(z_e, ch, cl, z2, e2, pc2);
  refine_kernel<<<M_ROWS / 4, 256, 0, stream>>>(z_e, cb, z2, e2, pc2, idxf, out + 4194304);
  gather_kernel<<<4096, 256, 0, stream>>>((const float4*)z_e, (const float4*)cb, idxf,
                                          (float4*)out, lpart, counts);
  finalize_kernel<<<1, 256, 0, stream>>>(lpart, counts, out + 4210688);
}

// Round 7
// 645.424 us; speedup vs baseline: 3.5867x; 1.2538x over previous
//
#include <hip/hip_runtime.h>

// Problem constants
#define M_ROWS 16384   // 32*512 z vectors
#define N_CB   8192    // codebook entries
#define KDIM   256     // code dim
#define NSPLIT 8
#define SPLITC (N_CB / NSPLIT)   // 1024 codes per split

#define FLTMAX 3.402823466e+38f

typedef __attribute__((ext_vector_type(8))) short short8v;  // 8 bf16 (4 VGPRs)
typedef __attribute__((ext_vector_type(4))) float f32x4;    // MFMA accumulator

__device__ __forceinline__ ushort bf16_rne(float x) {
  unsigned u = __float_as_uint(x);
  return (ushort)((u + 0x7FFF + ((u >> 16) & 1)) >> 16);   // RNE truncate to bf16
}

// ---------------- zero counts ----------------
__global__ __launch_bounds__(256) void zero_counts_kernel(int* counts) {
  int g = blockIdx.x * 256 + threadIdx.x;
  if (g < N_CB) counts[g] = 0;
}

// ---------------- row squared norms (one wave per row) ----------------
__global__ __launch_bounds__(256) void rowsq_kernel(const float4* __restrict__ ze4,
                                                    const float4* __restrict__ cb4,
                                                    float* __restrict__ z2,
                                                    float* __restrict__ e2) {
  int wave = blockIdx.x * 4 + (threadIdx.x >> 6);
  int lane = threadIdx.x & 63;
  float4 v;
  if (wave < M_ROWS) v = ze4[(size_t)wave * 64 + lane];
  else               v = cb4[(size_t)(wave - M_ROWS) * 64 + lane];
  float s = v.x * v.x + v.y * v.y + v.z * v.z + v.w * v.w;
  #pragma unroll
  for (int off = 32; off > 0; off >>= 1) s += __shfl_down(s, off, 64);
  if (lane == 0) {
    if (wave < M_ROWS) z2[wave] = s;
    else               e2[wave - M_ROWS] = s;
  }
}

// ---------------- codebook fp32 -> bf16 hi (lo no longer needed) ----------------
__global__ __launch_bounds__(256) void cbsplit_kernel(const float4* __restrict__ cb4,
                                                      ushort4* __restrict__ ch4) {
  int g = blockIdx.x * 256 + threadIdx.x;    // 0 .. 524287 (8192*64 float4)
  float4 v = cb4[g];
  ch4[g] = make_ushort4(bf16_rne(v.x), bf16_rne(v.y), bf16_rne(v.z), bf16_rne(v.w));
}

// ---------------- MFMA approx dist + per-(row,split) top-2, LDS-free ----------------
// dot(z,e) ~ eh*(zh+zl): 2 MFMAs per k-tile, err ~4e-6 (ok: typical min-to-2nd gap
// ~1e-3; exact refine resolves the 3e-5-grid ties among captured candidates).
// Roles (verified bit-exact in round 6): A = codebook tile (m=code), B = z tile
// (n=row).  A in:  lane l elem j -> A[l&15][(l>>4)*8+j]
//           B in:  lane l elem j -> B[(l>>4)*8+j][l&15]
//           D out: lane l reg  r -> D[m=(l>>4)*4+r][n=l&15]
// Each wave owns 16 z rows exclusively: B-frags live in 64 VGPRs for the whole
// kernel; A streams from global (L1-shared across the block's 4 waves). No LDS,
// no barriers, no bank conflicts.
__global__ __launch_bounds__(256) void mfma_topk_kernel(
    const float* __restrict__ A,      // z_e fp32 [16384][256]
    const ushort* __restrict__ ch,    // codebook hi bf16 bits [8192][256]
    const float* __restrict__ z2,
    const float* __restrict__ e2,
    int* __restrict__ pc2) {          // [NSPLIT][16384][2] candidate indices
  const int tid = threadIdx.x;
  const int w   = tid >> 6;
  const int l   = tid & 63;
  const int lg  = l >> 4;          // k-group (B) / m-subgroup (D)
  const int lr  = l & 15;          // z-row (B n, D col) / code-in-tile (A m)
  const int rowbase = blockIdx.x * 64 + w * 16;
  const int row = rowbase + lr;
  const int nb0 = blockIdx.y * SPLITC;

  // ---- B-frags: this lane's slice of 16 z rows, bf16 hi/lo, in registers ----
  short8v bh[8], bl[8];
  {
    const float* zp = A + (size_t)row * KDIM + lg * 8;
    #pragma unroll
    for (int ks = 0; ks < 8; ks++) {
      float4 v0 = *(const float4*)(zp + ks * 32);
      float4 v1 = *(const float4*)(zp + ks * 32 + 4);
      float vv[8] = {v0.x, v0.y, v0.z, v0.w, v1.x, v1.y, v1.z, v1.w};
      short8v h, lo;
      #pragma unroll
      for (int j = 0; j < 8; j++) {
        ushort hh = bf16_rne(vv[j]);
        float r = vv[j] - __uint_as_float((unsigned)hh << 16);
        h[j] = (short)hh;
        lo[j] = (short)bf16_rne(r);
      }
      bh[ks] = h; bl[ks] = lo;
    }
  }
  const float z2v = z2[row];

  float v1 = FLTMAX, v2 = FLTMAX;
  int   i1 = 0x7fffffff, i2 = 0x7fffffff;

  // ---- stream the split's 1024 codes as 64 A-tiles (2 tiles in flight) ----
  for (int ct = 0; ct < 64; ct += 2) {
    const ushort* a0 = ch + (size_t)(nb0 + ct * 16 + lr) * KDIM + lg * 8;
    const ushort* a1 = a0 + 16 * KDIM;
    f32x4 acc0 = {0.f, 0.f, 0.f, 0.f};
    f32x4 acc1 = {0.f, 0.f, 0.f, 0.f};
    #pragma unroll
    for (int ks = 0; ks < 8; ks++) {
      short8v f0 = *(const short8v*)(a0 + ks * 32);
      short8v f1 = *(const short8v*)(a1 + ks * 32);
      acc0 = __builtin_amdgcn_mfma_f32_16x16x32_bf16(f0, bh[ks], acc0, 0, 0, 0);
      acc0 = __builtin_amdgcn_mfma_f32_16x16x32_bf16(f0, bl[ks], acc0, 0, 0, 0);
      acc1 = __builtin_amdgcn_mfma_f32_16x16x32_bf16(f1, bh[ks], acc1, 0, 0, 0);
      acc1 = __builtin_amdgcn_mfma_f32_16x16x32_bf16(f1, bl[ks], acc1, 0, 0, 0);
    }
    // epilogue: codes ascending per lane (tile ct then ct+1, r ascending)
    float4 ea = *(const float4*)(e2 + nb0 + ct * 16 + lg * 4);
    float4 eb = *(const float4*)(e2 + nb0 + (ct + 1) * 16 + lg * 4);
    float eav[4] = {ea.x, ea.y, ea.z, ea.w};
    float ebv[4] = {eb.x, eb.y, eb.z, eb.w};
    #pragma unroll
    for (int r = 0; r < 4; r++) {
      int code = nb0 + ct * 16 + lg * 4 + r;
      float d = (z2v + eav[r]) - 2.0f * acc0[r];
      if (d < v1) { v2 = v1; i2 = i1; v1 = d; i1 = code; }
      else if (d < v2) { v2 = d; i2 = code; }
    }
    #pragma unroll
    for (int r = 0; r < 4; r++) {
      int code = nb0 + (ct + 1) * 16 + lg * 4 + r;
      float d = (z2v + ebv[r]) - 2.0f * acc1[r];
      if (d < v1) { v2 = v1; i2 = i1; v1 = d; i1 = code; }
      else if (d < v2) { v2 = d; i2 = code; }
    }
  }

  // ---- cross-lane top-2 merge: lanes l, l^16, l^32, l^48 share a row ----
  #pragma unroll
  for (int m = 16; m <= 32; m <<= 1) {
    float ov1 = __shfl_xor(v1, m, 64); int oi1 = __shfl_xor(i1, m, 64);
    float ov2 = __shfl_xor(v2, m, 64); int oi2 = __shfl_xor(i2, m, 64);
    if (ov1 < v1 || (ov1 == v1 && oi1 < i1)) {
      float nv2; int ni2;
      if (v1 < ov2 || (v1 == ov2 && i1 < oi2)) { nv2 = v1; ni2 = i1; }
      else { nv2 = ov2; ni2 = oi2; }
      v1 = ov1; i1 = oi1; v2 = nv2; i2 = ni2;
    } else {
      if (ov1 < v2 || (ov1 == v2 && oi1 < i2)) { v2 = ov1; i2 = oi1; }
    }
  }
  if (l < 16) {
    size_t gr = (size_t)blockIdx.y * M_ROWS + row;
    pc2[gr * 2]     = i1;
    pc2[gr * 2 + 1] = i2;
  }
}

// ---------------- exact fp32 refinement over 16 candidates per row ----------------
// One wave per row, 4 lanes per candidate. dist = fl(fl(z2+e2) - fl(2*dot)),
// lexicographic (dist, idx) min -> reference-exact semantics on the candidate set.
__global__ __launch_bounds__(256) void refine_kernel(
    const float* __restrict__ z_e, const float* __restrict__ cb,
    const float* __restrict__ z2, const float* __restrict__ e2,
    const int* __restrict__ pc2,
    int* __restrict__ idxf, float* __restrict__ codes_out) {
  __shared__ float rv[4][16];
  __shared__ int   ri[4][16];
  int wv = threadIdx.x >> 6;
  int l  = threadIdx.x & 63;
  int row = blockIdx.x * 4 + wv;
  int c = l >> 2, q = l & 3;
  int split = c >> 1, ent = c & 1;
  int cand = pc2[((size_t)split * M_ROWS + row) * 2 + ent];
  const float4* zr = (const float4*)(z_e + (size_t)row * KDIM);
  const float4* cr = (const float4*)(cb + (size_t)cand * KDIM);
  float s = 0.0f;
  #pragma unroll
  for (int j = 0; j < 16; j++) {
    float4 a = zr[q + 4 * j];
    float4 b = cr[q + 4 * j];
    s = fmaf(a.x, b.x, s); s = fmaf(a.y, b.y, s);
    s = fmaf(a.z, b.z, s); s = fmaf(a.w, b.w, s);
  }
  s += __shfl_xor(s, 1);
  s += __shfl_xor(s, 2);
  if (q == 0) {
    float d = (z2[row] + e2[cand]) - 2.0f * s;
    rv[wv][c] = d; ri[wv][c] = cand;
  }
  __syncthreads();
  if (l == 0) {
    float bv = rv[wv][0]; int bi = ri[wv][0];
    for (int k = 1; k < 16; k++) {
      float v = rv[wv][k]; int ii = ri[wv][k];
      if (v < bv || (v == bv && ii < bi)) { bv = v; bi = ii; }
    }
    idxf[row] = bi;
    codes_out[row] = (float)bi;
  }
}

// ---------------- gather z_q, write z_q_st, loss partials, histogram ----------------
__global__ __launch_bounds__(256) void gather_kernel(const float4* __restrict__ ze4,
                                                     const float4* __restrict__ cb4,
                                                     const int* __restrict__ idx,
                                                     float4* __restrict__ out4,
                                                     float* __restrict__ lpart,
                                                     int* __restrict__ counts) {
  int g = blockIdx.x * 256 + threadIdx.x;
  int row = g >> 6;
  int c4 = g & 63;
  int lane = threadIdx.x & 63;
  int code = idx[row];
  float4 z = ze4[(size_t)row * 64 + c4];
  float4 e = cb4[(size_t)code * 64 + c4];
  float dx = e.x - z.x, dy = e.y - z.y, dz = e.z - z.z, dw = e.w - z.w;
  float4 o;
  o.x = z.x + dx; o.y = z.y + dy; o.z = z.z + dz; o.w = z.w + dw;
  out4[(size_t)row * 64 + c4] = o;
  float ls = dx * dx + dy * dy + dz * dz + dw * dw;
  #pragma unroll
  for (int off = 32; off > 0; off >>= 1) ls += __shfl_down(ls, off, 64);
  __shared__ float sred[4];
  if (lane == 0) {
    sred[threadIdx.x >> 6] = ls;
    atomicAdd(&counts[code], 1);
  }
  __syncthreads();
  if (threadIdx.x == 0) lpart[blockIdx.x] = sred[0] + sred[1] + sred[2] + sred[3];
}

// ---------------- finalize scalars ----------------
__global__ __launch_bounds__(256) void finalize_kernel(const float* __restrict__ lpart,
                                                       const int* __restrict__ counts,
                                                       float* __restrict__ out_scalars) {
  __shared__ double sd[256];
  double s = 0.0;
  for (int i = threadIdx.x; i < 4096; i += 256) s += (double)lpart[i];
  sd[threadIdx.x] = s;
  __syncthreads();
  for (int st = 128; st > 0; st >>= 1) {
    if (threadIdx.x < st) sd[threadIdx.x] += sd[threadIdx.x + st];
    __syncthreads();
  }
  double totalLoss = sd[0];
  __syncthreads();
  double ps = 0.0;
  for (int c = threadIdx.x; c < N_CB; c += 256) {
    float avg = (float)counts[c] * (1.0f / 16384.0f);
    ps += (double)(avg * logf(avg + 1e-10f));
  }
  sd[threadIdx.x] = ps;
  __syncthreads();
  for (int st = 128; st > 0; st >>= 1) {
    if (threadIdx.x < st) sd[threadIdx.x] += sd[threadIdx.x + st];
    __syncthreads();
  }
  if (threadIdx.x == 0) {
    float mean = (float)(totalLoss / 4194304.0);
    float lv = mean + 0.25f * mean;
    out_scalars[0] = lv;
    out_scalars[1] = expf(-(float)sd[0]);
  }
}

extern "C" void kernel_launch(void* const* d_in, const int* in_sizes, int n_in,
                              void* d_out, int out_size, void* d_ws, size_t ws_size,
                              hipStream_t stream) {
  const float* z_e = (const float*)d_in[0];   // 32*512*256
  const float* cb  = (const float*)d_in[1];   // 8192*256
  float* out = (float*)d_out;
  // out layout: [0,4194304) z_q_st | [4194304,4210688) codes(float) | loss | perplexity

  char* ws = (char*)d_ws;
  ushort* ch   = (ushort*)(ws + 0);          // 8192*256 bf16 hi (4 MB)
  float* z2    = (float*)(ws + 4194304);     // 16384 f32 (64 KB)
  float* e2    = (float*)(ws + 4259840);     // 8192 f32 (32 KB)
  int*   pc2   = (int*)  (ws + 4292608);     // 8*16384*2 i32 (1 MB)
  int*   idxf  = (int*)  (ws + 5341184);     // 16384 i32 (64 KB)
  int*   counts= (int*)  (ws + 5406720);     // 8192 i32 (32 KB)
  float* lpart = (float*)(ws + 5439488);     // 4096 f32 (16 KB)
  // total ws use: ~5.45 MB

  zero_counts_kernel<<<32, 256, 0, stream>>>(counts);
  rowsq_kernel<<<(M_ROWS + N_CB) / 4, 256, 0, stream>>>(
      (const float4*)z_e, (const float4*)cb, z2, e2);
  cbsplit_kernel<<<2048, 256, 0, stream>>>((const float4*)cb, (ushort4*)ch);
  dim3 grid(M_ROWS / 64, NSPLIT);
  mfma_topk_kernel<<<grid, 256, 0, stream>>>(z_e, ch, z2, e2, pc2);
  refine_kernel<<<M_ROWS / 4, 256, 0, stream>>>(z_e, cb, z2, e2, pc2, idxf, out + 4194304);
  gather_kernel<<<4096, 256, 0, stream>>>((const float4*)z_e, (const float4*)cb, idxf,
                                          (float4*)out, lpart, counts);
  finalize_kernel<<<1, 256, 0, stream>>>(lpart, counts, out + 4210688);
}

// Round 8
// 239.981 us; speedup vs baseline: 9.6463x; 2.6895x over previous
//
#include <hip/hip_runtime.h>

// Problem constants
#define M_ROWS 16384   // 32*512 z vectors
#define N_CB   8192    // codebook entries
#define KDIM   256     // code dim
#define NSPLIT 8
#define SPLITC 1024    // codes per split
#define TILES  64      // 16-code tiles per split

#define FLTMAX 3.402823466e+38f

typedef __attribute__((ext_vector_type(8))) short short8v;  // 8 bf16 (4 VGPRs)
typedef __attribute__((ext_vector_type(4))) float f32x4;    // MFMA accumulator

typedef __attribute__((address_space(3))) unsigned int lds_u32;
typedef __attribute__((address_space(1))) const unsigned int glb_u32;

__device__ __forceinline__ ushort bf16_rne(float x) {
  unsigned u = __float_as_uint(x);
  return (ushort)((u + 0x7FFF + ((u >> 16) & 1)) >> 16);   // RNE to bf16
}

// ---------------- zero counts ----------------
__global__ __launch_bounds__(256) void zero_counts_kernel(int* counts) {
  int g = blockIdx.x * 256 + threadIdx.x;
  if (g < N_CB) counts[g] = 0;
}

// ---------------- row squared norms (one wave per row) — for refine ----------------
__global__ __launch_bounds__(256) void rowsq_kernel(const float4* __restrict__ ze4,
                                                    const float4* __restrict__ cb4,
                                                    float* __restrict__ z2,
                                                    float* __restrict__ e2) {
  int wave = blockIdx.x * 4 + (threadIdx.x >> 6);
  int lane = threadIdx.x & 63;
  float4 v;
  if (wave < M_ROWS) v = ze4[(size_t)wave * 64 + lane];
  else               v = cb4[(size_t)(wave - M_ROWS) * 64 + lane];
  float s = v.x * v.x + v.y * v.y + v.z * v.z + v.w * v.w;
  #pragma unroll
  for (int off = 32; off > 0; off >>= 1) s += __shfl_down(s, off, 64);
  if (lane == 0) {
    if (wave < M_ROWS) z2[wave] = s;
    else               e2[wave - M_ROWS] = s;
  }
}

// ---------------- codebook fp32 -> bf16, PERMUTED to A-fragment lane order ----------
// chP layout: [tile=c/16][ks=k/32][lane=lg*16+lr][j=0..7] where lr=c&15,
// lg=(k&31)>>3, j=k&7.  A wave's ds_read_b128 at (ks*512 + l*8) ushorts is then
// lane-linear (conflict-free) AND global_load_lds stages it with the required
// wave-uniform-base + lane*16B pattern.
__global__ __launch_bounds__(256) void cbperm_kernel(const float4* __restrict__ cb4,
                                                     ushort* __restrict__ chP) {
  int g = blockIdx.x * 256 + threadIdx.x;   // 0..524287 (8192 codes * 64 float4)
  int c = g >> 6, kq = g & 63;
  int k = kq * 4;
  int tile = c >> 4, lr = c & 15, ks = k >> 5, lg = (k & 31) >> 3, j = k & 7;
  float4 v = cb4[g];
  size_t off = ((size_t)(tile * 8 + ks) * 64 + lg * 16 + lr) * 8 + j;
  *(ushort4*)(chP + off) = make_ushort4(bf16_rne(v.x), bf16_rne(v.y),
                                        bf16_rne(v.z), bf16_rne(v.w));
}

// ---------------- MFMA max-dot + per-(row,split) top-2 ----------------
// Candidate ranking needs only the dot product: e2max=3.8e-6 < half-ulp(z2) so
// fl(z2+e2)==z2 in the reference, and z2 is a per-row constant. 1-term zh*eh
// (noise ~4e-6 on dist scale, << ~5e-4 min-to-2nd gaps; refine is exact).
// Block: 4 waves x 32 rows = 128 rows; streams its split's 64 code-tiles
// through a 4-slot LDS ring staged by global_load_lds, counted vmcnt(4),
// raw s_barrier (never drain to 0 in the loop).
__global__ __launch_bounds__(256) void mfma_topk_kernel(
    const ushort* __restrict__ chP,
    const float* __restrict__ z_e,
    int* __restrict__ pc2) {          // [NSPLIT][M_ROWS][2]
  __shared__ __align__(16) ushort lds[4][4096];   // 4 slots x 8KB

  const int tid = threadIdx.x;
  const int w = tid >> 6, l = tid & 63;
  const int lg = l >> 4, lr = l & 15;
  const int rowbase = blockIdx.x * 128 + w * 32;  // wave-exclusive 32 rows
  const int tile0 = blockIdx.y * TILES;

  // ---- B-frags: 2 row-tiles x 8 ks, bf16(z) in registers (64 VGPR) ----
  short8v bh0[8], bh1[8];
  {
    const float* zp0 = z_e + (size_t)(rowbase + lr) * KDIM + lg * 8;
    const float* zp1 = zp0 + 16 * KDIM;
    #pragma unroll
    for (int ks = 0; ks < 8; ks++) {
      float4 a = *(const float4*)(zp0 + ks * 32);
      float4 b = *(const float4*)(zp0 + ks * 32 + 4);
      short8v h;
      h[0] = (short)bf16_rne(a.x); h[1] = (short)bf16_rne(a.y);
      h[2] = (short)bf16_rne(a.z); h[3] = (short)bf16_rne(a.w);
      h[4] = (short)bf16_rne(b.x); h[5] = (short)bf16_rne(b.y);
      h[6] = (short)bf16_rne(b.z); h[7] = (short)bf16_rne(b.w);
      bh0[ks] = h;
      float4 c = *(const float4*)(zp1 + ks * 32);
      float4 d = *(const float4*)(zp1 + ks * 32 + 4);
      short8v h2;
      h2[0] = (short)bf16_rne(c.x); h2[1] = (short)bf16_rne(c.y);
      h2[2] = (short)bf16_rne(c.z); h2[3] = (short)bf16_rne(c.w);
      h2[4] = (short)bf16_rne(d.x); h2[5] = (short)bf16_rne(d.y);
      h2[6] = (short)bf16_rne(d.z); h2[7] = (short)bf16_rne(d.w);
      bh1[ks] = h2;
    }
  }
  // Drain prologue vmem so loop vmcnt counting sees ONLY staging loads.
  asm volatile("s_waitcnt vmcnt(0)" ::: "memory");

  // Each wave stages ushorts [w*1024, w*1024+1024) of the 4KB tile: 2 calls.
#define STAGE(T) { \
    const ushort* _src = chP + (size_t)(tile0 + (T)) * 4096 + w * 1024 + l * 8; \
    ushort* _dst = &lds[(T) & 3][w * 1024]; \
    __builtin_amdgcn_global_load_lds((glb_u32*)_src, (lds_u32*)_dst, 16, 0, 0); \
    __builtin_amdgcn_global_load_lds((glb_u32*)(_src + 512), (lds_u32*)(_dst + 512), 16, 0, 0); }

  float v1a = -FLTMAX, v2a = -FLTMAX, v1b = -FLTMAX, v2b = -FLTMAX;
  int i1a = 0x7fffffff, i2a = 0x7fffffff, i1b = 0x7fffffff, i2b = 0x7fffffff;

#define COMPUTE(T) { \
    const ushort* sl = &lds[(T) & 3][0]; \
    f32x4 a0 = {0.f, 0.f, 0.f, 0.f}, a1 = {0.f, 0.f, 0.f, 0.f}; \
    _Pragma("unroll") \
    for (int ks = 0; ks < 8; ks++) { \
      short8v f = *(const short8v*)(sl + ks * 512 + l * 8); \
      a0 = __builtin_amdgcn_mfma_f32_16x16x32_bf16(f, bh0[ks], a0, 0, 0, 0); \
      a1 = __builtin_amdgcn_mfma_f32_16x16x32_bf16(f, bh1[ks], a1, 0, 0, 0); \
    } \
    const int cbase = (tile0 + (T)) * 16 + lg * 4; \
    _Pragma("unroll") \
    for (int r = 0; r < 4; r++) { \
      int cc = cbase + r; \
      float d0 = a0[r]; \
      if (d0 > v1a) { v2a = v1a; i2a = i1a; v1a = d0; i1a = cc; } \
      else if (d0 > v2a) { v2a = d0; i2a = cc; } \
      float d1 = a1[r]; \
      if (d1 > v1b) { v2b = v1b; i2b = i1b; v1b = d1; i1b = cc; } \
      else if (d1 > v2b) { v2b = d1; i2b = cc; } \
    } }

  STAGE(0) STAGE(1) STAGE(2)
  for (int t = 0; t < 61; ++t) {
    asm volatile("s_waitcnt vmcnt(4)" ::: "memory");   // own tile-t calls done
    __builtin_amdgcn_s_barrier();                      // all waves' pieces done
    __builtin_amdgcn_sched_barrier(0);                 // no ds_read hoist past barrier
    STAGE(t + 3)                                       // slot (t-1)&3 free after barrier
    COMPUTE(t)
  }
  asm volatile("s_waitcnt vmcnt(4)" ::: "memory");
  __builtin_amdgcn_s_barrier();
  __builtin_amdgcn_sched_barrier(0);
  COMPUTE(61)
  asm volatile("s_waitcnt vmcnt(2)" ::: "memory");
  __builtin_amdgcn_s_barrier();
  __builtin_amdgcn_sched_barrier(0);
  COMPUTE(62)
  asm volatile("s_waitcnt vmcnt(0)" ::: "memory");
  __builtin_amdgcn_s_barrier();
  __builtin_amdgcn_sched_barrier(0);
  COMPUTE(63)

  // ---- cross-lane top-2 merge over lg group (max dot, tie -> lower index) ----
#define MERGE2(V1, I1, V2, I2) \
    _Pragma("unroll") \
    for (int m = 16; m <= 32; m <<= 1) { \
      float ov1 = __shfl_xor(V1, m, 64); int oi1 = __shfl_xor(I1, m, 64); \
      float ov2 = __shfl_xor(V2, m, 64); int oi2 = __shfl_xor(I2, m, 64); \
      if (ov1 > V1 || (ov1 == V1 && oi1 < I1)) { \
        if (V1 > ov2 || (V1 == ov2 && I1 < oi2)) { V2 = V1; I2 = I1; } \
        else { V2 = ov2; I2 = oi2; } \
        V1 = ov1; I1 = oi1; \
      } else if (ov1 > V2 || (ov1 == V2 && oi1 < I2)) { V2 = ov1; I2 = oi1; } \
    }

  MERGE2(v1a, i1a, v2a, i2a)
  MERGE2(v1b, i1b, v2b, i2b)
  if (l < 16) {
    size_t g0 = (size_t)blockIdx.y * M_ROWS + rowbase + lr;
    pc2[g0 * 2]     = i1a;
    pc2[g0 * 2 + 1] = i2a;
    size_t g1 = g0 + 16;
    pc2[g1 * 2]     = i1b;
    pc2[g1 * 2 + 1] = i2b;
  }
#undef STAGE
#undef COMPUTE
#undef MERGE2
}

// ---------------- exact fp32 refinement over 16 candidates per row ----------------
// One wave per row, 4 lanes per candidate. dist = fl(fl(z2+e2) - fl(2*dot)),
// lexicographic (dist, idx) min -> reference-exact semantics on the candidate set.
__global__ __launch_bounds__(256) void refine_kernel(
    const float* __restrict__ z_e, const float* __restrict__ cb,
    const float* __restrict__ z2, const float* __restrict__ e2,
    const int* __restrict__ pc2,
    int* __restrict__ idxf, float* __restrict__ codes_out) {
  __shared__ float rv[4][16];
  __shared__ int   ri[4][16];
  int wv = threadIdx.x >> 6;
  int l  = threadIdx.x & 63;
  int row = blockIdx.x * 4 + wv;
  int c = l >> 2, q = l & 3;
  int split = c >> 1, ent = c & 1;
  int cand = pc2[((size_t)split * M_ROWS + row) * 2 + ent];
  const float4* zr = (const float4*)(z_e + (size_t)row * KDIM);
  const float4* cr = (const float4*)(cb + (size_t)cand * KDIM);
  float s = 0.0f;
  #pragma unroll
  for (int j = 0; j < 16; j++) {
    float4 a = zr[q + 4 * j];
    float4 b = cr[q + 4 * j];
    s = fmaf(a.x, b.x, s); s = fmaf(a.y, b.y, s);
    s = fmaf(a.z, b.z, s); s = fmaf(a.w, b.w, s);
  }
  s += __shfl_xor(s, 1);
  s += __shfl_xor(s, 2);
  if (q == 0) {
    float d = (z2[row] + e2[cand]) - 2.0f * s;
    rv[wv][c] = d; ri[wv][c] = cand;
  }
  __syncthreads();
  if (l == 0) {
    float bv = rv[wv][0]; int bi = ri[wv][0];
    for (int k = 1; k < 16; k++) {
      float v = rv[wv][k]; int ii = ri[wv][k];
      if (v < bv || (v == bv && ii < bi)) { bv = v; bi = ii; }
    }
    idxf[row] = bi;
    codes_out[row] = (float)bi;
  }
}

// ---------------- gather z_q, write z_q_st, loss partials, histogram ----------------
__global__ __launch_bounds__(256) void gather_kernel(const float4* __restrict__ ze4,
                                                     const float4* __restrict__ cb4,
                                                     const int* __restrict__ idx,
                                                     float4* __restrict__ out4,
                                                     float* __restrict__ lpart,
                                                     int* __restrict__ counts) {
  int g = blockIdx.x * 256 + threadIdx.x;
  int row = g >> 6;
  int c4 = g & 63;
  int lane = threadIdx.x & 63;
  int code = idx[row];
  float4 z = ze4[(size_t)row * 64 + c4];
  float4 e = cb4[(size_t)code * 64 + c4];
  float dx = e.x - z.x, dy = e.y - z.y, dz = e.z - z.z, dw = e.w - z.w;
  float4 o;
  o.x = z.x + dx; o.y = z.y + dy; o.z = z.z + dz; o.w = z.w + dw;
  out4[(size_t)row * 64 + c4] = o;
  float ls = dx * dx + dy * dy + dz * dz + dw * dw;
  #pragma unroll
  for (int off = 32; off > 0; off >>= 1) ls += __shfl_down(ls, off, 64);
  __shared__ float sred[4];
  if (lane == 0) {
    sred[threadIdx.x >> 6] = ls;
    atomicAdd(&counts[code], 1);
  }
  __syncthreads();
  if (threadIdx.x == 0) lpart[blockIdx.x] = sred[0] + sred[1] + sred[2] + sred[3];
}

// ---------------- finalize scalars ----------------
__global__ __launch_bounds__(256) void finalize_kernel(const float* __restrict__ lpart,
                                                       const int* __restrict__ counts,
                                                       float* __restrict__ out_scalars) {
  __shared__ double sd[256];
  double s = 0.0;
  for (int i = threadIdx.x; i < 4096; i += 256) s += (double)lpart[i];
  sd[threadIdx.x] = s;
  __syncthreads();
  for (int st = 128; st > 0; st >>= 1) {
    if (threadIdx.x < st) sd[threadIdx.x] += sd[threadIdx.x + st];
    __syncthreads();
  }
  double totalLoss = sd[0];
  __syncthreads();
  double ps = 0.0;
  for (int c = threadIdx.x; c < N_CB; c += 256) {
    float avg = (float)counts[c] * (1.0f / 16384.0f);
    ps += (double)(avg * logf(avg + 1e-10f));
  }
  sd[threadIdx.x] = ps;
  __syncthreads();
  for (int st = 128; st > 0; st >>= 1) {
    if (threadIdx.x < st) sd[threadIdx.x] += sd[threadIdx.x + st];
    __syncthreads();
  }
  if (threadIdx.x == 0) {
    float mean = (float)(totalLoss / 4194304.0);
    float lv = mean + 0.25f * mean;
    out_scalars[0] = lv;
    out_scalars[1] = expf(-(float)sd[0]);
  }
}

extern "C" void kernel_launch(void* const* d_in, const int* in_sizes, int n_in,
                              void* d_out, int out_size, void* d_ws, size_t ws_size,
                              hipStream_t stream) {
  const float* z_e = (const float*)d_in[0];   // 32*512*256
  const float* cb  = (const float*)d_in[1];   // 8192*256
  float* out = (float*)d_out;
  // out layout: [0,4194304) z_q_st | [4194304,4210688) codes(float) | loss | perplexity

  char* ws = (char*)d_ws;
  ushort* chP  = (ushort*)(ws + 0);          // permuted bf16 codebook (4 MB)
  float* z2    = (float*)(ws + 4194304);     // 16384 f32
  float* e2    = (float*)(ws + 4259840);     // 8192 f32
  int*   pc2   = (int*)  (ws + 4292608);     // 8*16384*2 i32 (1 MB)
  int*   idxf  = (int*)  (ws + 5341184);     // 16384 i32
  int*   counts= (int*)  (ws + 5406720);     // 8192 i32
  float* lpart = (float*)(ws + 5439488);     // 4096 f32
  // total ws use: ~5.45 MB

  zero_counts_kernel<<<32, 256, 0, stream>>>(counts);
  rowsq_kernel<<<(M_ROWS + N_CB) / 4, 256, 0, stream>>>(
      (const float4*)z_e, (const float4*)cb, z2, e2);
  cbperm_kernel<<<2048, 256, 0, stream>>>((const float4*)cb, chP);
  dim3 grid(M_ROWS / 128, NSPLIT);
  mfma_topk_kernel<<<grid, 256, 0, stream>>>(chP, z_e, pc2);
  refine_kernel<<<M_ROWS / 4, 256, 0, stream>>>(z_e, cb, z2, e2, pc2, idxf, out + 4194304);
  gather_kernel<<<4096, 256, 0, stream>>>((const float4*)z_e, (const float4*)cb, idxf,
                                          (float4*)out, lpart, counts);
  finalize_kernel<<<1, 256, 0, stream>>>(lpart, counts, out + 4210688);
}